// Round 9
// baseline (735.287 us; speedup 1.0000x reference)
//
#include <hip/hip_runtime.h>
#include <hip/hip_bf16.h>

#define NIMG 16
#define IN_CH 512
#define OUT_CH 256
#define HIN 64
#define HOUT 128
#define HP 66  // padded spatial (1-pixel zero halo)

#define WSCALE 0.014731391f      // 1/sqrt(9*512)
#define ACT_GAIN 1.41421356237f  // sqrt(2)
#define CLAMP_V 256.0f

typedef __attribute__((ext_vector_type(8))) short bf16x8;
typedef __attribute__((ext_vector_type(4))) float f32x4;
typedef __attribute__((ext_vector_type(16))) float f32x16;

// Parity tap matrices: G[p][i][a] = u[a-1+2i-p], u = {1,3,3,1}/4 (0 if OOR)
__device__ __constant__ float c_G[2][3][3] = {
    {{0.00f, 0.25f, 0.75f}, {0.75f, 0.75f, 0.25f}, {0.25f, 0.00f, 0.00f}},
    {{0.00f, 0.00f, 0.25f}, {0.25f, 0.75f, 0.75f}, {0.75f, 0.25f, 0.00f}}
};

#define XBF_BYTES ((size_t)NIMG * HP * HP * IN_CH * 2)     // 71,368,704
#define EBF_BYTES ((size_t)9 * 1024 * IN_CH * 2)           //  9,437,184
#define WS_NEED (XBF_BYTES + EBF_BYTES)

// ---------------- x -> padded NHWC bf16 [16][66][66][512] ----------------
__global__ __launch_bounds__(256) void xpose_kernel(const float* __restrict__ x,
                                                    __hip_bfloat16* __restrict__ xbf) {
    const int n = blockIdx.z;
    const int hp = blockIdx.y;        // 0..65
    const int c0 = blockIdx.x << 6;   // 8 chunks of 64 channels
    const int tid = threadIdx.x;
    const size_t obase = ((size_t)n * HP + hp) * HP;  // pixel-row base

    if (hp == 0 || hp == HP - 1) {
        for (int idx = tid; idx < HP * 64; idx += 256) {
            int wp = idx >> 6, c = idx & 63;
            xbf[(obase + wp) * IN_CH + c0 + c] = __float2bfloat16(0.f);
        }
        return;
    }
    __shared__ float tile[64][65];
    {
        int cc = tid >> 6, w = tid & 63;
        for (int cb = 0; cb < 64; cb += 4)
            tile[cb + cc][w] =
                x[(((size_t)n * IN_CH + c0 + cb + cc) * HIN + (hp - 1)) * HIN + w];
    }
    __syncthreads();
    {
        int c = tid & 63, wg = tid >> 6;
        for (int wb = 0; wb < 64; wb += 4) {
            int w2 = wb + wg;
            xbf[(obase + (w2 + 1)) * IN_CH + c0 + c] = __float2bfloat16(tile[c][w2]);
        }
        if (tid < 128) {
            int which = tid >> 6, c2 = tid & 63;
            xbf[(obase + (which ? (HP - 1) : 0)) * IN_CH + c0 + c2] = __float2bfloat16(0.f);
        }
    }
}

// ---------------- w -> E bf16 [9(tap)][1024(oc*4+par)][512(c)] ----------------
__global__ __launch_bounds__(256) void build_ebf_kernel(const float* __restrict__ w,
                                                        __hip_bfloat16* __restrict__ ebf) {
    int gid = blockIdx.x * 256 + threadIdx.x;  // oc*512 + c
    if (gid >= OUT_CH * IN_CH) return;
    int oc = gid >> 9, c = gid & 511;
    float wm[3][3];
    const float* wp = w + (size_t)gid * 9;
#pragma unroll
    for (int a = 0; a < 3; ++a)
#pragma unroll
        for (int b = 0; b < 3; ++b) wm[a][b] = wp[a * 3 + b] * WSCALE;
#pragma unroll
    for (int i = 0; i < 3; ++i)
#pragma unroll
        for (int j = 0; j < 3; ++j)
#pragma unroll
            for (int pu = 0; pu < 2; ++pu)
#pragma unroll
                for (int pv = 0; pv < 2; ++pv) {
                    float s = 0.f;
#pragma unroll
                    for (int a = 0; a < 3; ++a)
#pragma unroll
                        for (int b = 0; b < 3; ++b)
                            s += wm[a][b] * c_G[pu][i][a] * c_G[pv][j][b];
                    ebf[((size_t)(i * 3 + j) * 1024 + oc * 4 + pu * 2 + pv) * IN_CH + c] =
                        __float2bfloat16(s);
                }
}

// 8 MFMAs of 32x32x16: AF[mt2*2+ks], BF[nt*2+ks]; acc[MH*4 + mt2*2 + nt].
#define MFMA8(AF, BF, MH)                                                                   \
    do {                                                                                    \
        acc[(MH)*4+0] = __builtin_amdgcn_mfma_f32_32x32x16_bf16((AF)[0], (BF)[0], acc[(MH)*4+0], 0, 0, 0); \
        acc[(MH)*4+1] = __builtin_amdgcn_mfma_f32_32x32x16_bf16((AF)[0], (BF)[2], acc[(MH)*4+1], 0, 0, 0); \
        acc[(MH)*4+2] = __builtin_amdgcn_mfma_f32_32x32x16_bf16((AF)[2], (BF)[0], acc[(MH)*4+2], 0, 0, 0); \
        acc[(MH)*4+3] = __builtin_amdgcn_mfma_f32_32x32x16_bf16((AF)[2], (BF)[2], acc[(MH)*4+3], 0, 0, 0); \
        acc[(MH)*4+0] = __builtin_amdgcn_mfma_f32_32x32x16_bf16((AF)[1], (BF)[1], acc[(MH)*4+0], 0, 0, 0); \
        acc[(MH)*4+1] = __builtin_amdgcn_mfma_f32_32x32x16_bf16((AF)[1], (BF)[3], acc[(MH)*4+1], 0, 0, 0); \
        acc[(MH)*4+2] = __builtin_amdgcn_mfma_f32_32x32x16_bf16((AF)[3], (BF)[1], acc[(MH)*4+2], 0, 0, 0); \
        acc[(MH)*4+3] = __builtin_amdgcn_mfma_f32_32x32x16_bf16((AF)[3], (BF)[3], acc[(MH)*4+3], 0, 0, 0); \
    } while (0)

// GLL-pair src deltas (bytes): +64 rows
#define CDA 270336   // A: +4 quad-rows of padded image: 4*66*512*2
#define CDB 65536    // B: +64 rows of E: 64*512*2
// LDS dst slot constants (bytes), PAR literal
#define DAK1(PAR) (((((PAR) ^ 1) << 2) | 1) << 14)
#define DBK1(PAR) (((((PAR) ^ 1) << 2) | 3) << 14)
#define DAK0(PAR) ((((PAR) << 2) | 0) << 14)
#define DBK0(PAR) ((((PAR) << 2) | 2) << 14)

#define GLL(SRC, DSTOFF)                                                          \
    __builtin_amdgcn_global_load_lds(                                             \
        (const __attribute__((address_space(1))) unsigned int*)(SRC),             \
        (__attribute__((address_space(3))) unsigned int*)(ldsW + (DSTOFF)), 16, 0, 0)

// One K-tile (BK=64), 4 phases, PAR = tile parity LITERAL.
// Schedule/ledger identical to R6/R7 (lgkm 4/8/4/8, vmcnt at p0/p2, 1 barrier/phase).
// LDS half-slot layout: [slice(8ch) 4][row 256 x 16B], off = slice*4096 +
// (row*16 ^ (row&32?64:0) ^ (slice&1?64:0)). Frag reads are contiguous-16B-per-lane
// within each 32-lane run and half-waves land in disjoint 64B windows ->
// conflict-free under consecutive-8, cross-half-paired, and 16-contig groupings.
// Write side: linear GLL dest (64-row runs); row-permuted per-lane global SOURCE.
#define TILE_ITER(PAR, TT, SP01, SP23, VMS, LGK3, LAST)                           \
    {                                                                             \
        const int A0 = (PAR) ? aM0O : aM0E;                                       \
        const int A1 = (PAR) ? aM1O : aM1E;                                       \
        const int B0 = (PAR) ? bN0O : bN0E;                                       \
        const int B1 = (PAR) ? bN1O : bN1E;                                       \
        /* ---- p0: compute (kh0,mh0) afE,b0; prefetch afO<-(kh0,mh1); stage AK1 */\
        afO[0] = *(const bf16x8*)&lds[A0 + 1024];                                 \
        afO[1] = *(const bf16x8*)&lds[A0 + 1024 + 8192];                          \
        afO[2] = *(const bf16x8*)&lds[A1 + 1024];                                 \
        afO[3] = *(const bf16x8*)&lds[A1 + 1024 + 8192];                          \
        if (SP01) { GLL(xbc + sA1 + voffA, DAK1(PAR));                            \
                    GLL(xbc + sA1 + voffA + CDA, DAK1(PAR) + 1024); }             \
        sA1 += ((TT) == 22 || (TT) == 46) ? 64640 : 128;                          \
        asm volatile("s_waitcnt lgkmcnt(4)" ::: "memory");                        \
        __builtin_amdgcn_sched_barrier(0);                                        \
        __builtin_amdgcn_s_setprio(1);                                            \
        MFMA8(afE, b0, 0);                                                        \
        __builtin_amdgcn_s_setprio(0);                                            \
        asm volatile("s_waitcnt " VMS ::: "memory");                              \
        __builtin_amdgcn_s_barrier();                                             \
        __builtin_amdgcn_sched_barrier(0);                                        \
        /* ---- p1: compute (kh0,mh1) afO,b0; prefetch afE<-(kh1,mh0)+b1; BK1 */  \
        afE[0] = *(const bf16x8*)&lds[A0 + 16384];                                \
        afE[1] = *(const bf16x8*)&lds[A0 + 16384 + 8192];                         \
        afE[2] = *(const bf16x8*)&lds[A1 + 16384];                                \
        afE[3] = *(const bf16x8*)&lds[A1 + 16384 + 8192];                         \
        b1[0] = *(const bf16x8*)&lds[B0 + 16384];                                 \
        b1[1] = *(const bf16x8*)&lds[B0 + 16384 + 8192];                          \
        b1[2] = *(const bf16x8*)&lds[B1 + 16384];                                 \
        b1[3] = *(const bf16x8*)&lds[B1 + 16384 + 8192];                          \
        if (SP01) { GLL(ebc + sB1 + voffB, DBK1(PAR));                            \
                    GLL(ebc + sB1 + voffB + CDB, DBK1(PAR) + 1024); }             \
        sB1 += (((TT) & 7) == 6) ? 1047680 : 128;                                 \
        asm volatile("s_waitcnt lgkmcnt(8)" ::: "memory");                        \
        __builtin_amdgcn_sched_barrier(0);                                        \
        __builtin_amdgcn_s_setprio(1);                                            \
        MFMA8(afO, b0, 1);                                                        \
        __builtin_amdgcn_s_setprio(0);                                            \
        __builtin_amdgcn_s_barrier();                                             \
        __builtin_amdgcn_sched_barrier(0);                                        \
        /* ---- p2: compute (kh1,mh0) afE,b1; prefetch afO<-(kh1,mh1); stage AK0 */\
        afO[0] = *(const bf16x8*)&lds[A0 + 16384 + 1024];                         \
        afO[1] = *(const bf16x8*)&lds[A0 + 16384 + 1024 + 8192];                  \
        afO[2] = *(const bf16x8*)&lds[A1 + 16384 + 1024];                         \
        afO[3] = *(const bf16x8*)&lds[A1 + 16384 + 1024 + 8192];                  \
        if (SP23) { GLL(xbc + sA0 + voffA, DAK0(PAR));                            \
                    GLL(xbc + sA0 + voffA + CDA, DAK0(PAR) + 1024); }             \
        sA0 += ((TT) == 21 || (TT) == 45) ? 64640 : 128;                          \
        asm volatile("s_waitcnt lgkmcnt(4)" ::: "memory");                        \
        __builtin_amdgcn_sched_barrier(0);                                        \
        __builtin_amdgcn_s_setprio(1);                                            \
        MFMA8(afE, b1, 0);                                                        \
        __builtin_amdgcn_s_setprio(0);                                            \
        asm volatile("s_waitcnt " VMS ::: "memory");                              \
        __builtin_amdgcn_s_barrier();                                             \
        __builtin_amdgcn_sched_barrier(0);                                        \
        /* ---- p3: compute (kh1,mh1) afO,b1; prefetch next tile afE,b0; BK0 */   \
        if (!(LAST)) {                                                            \
            const int nA0 = (PAR) ? aM0E : aM0O;                                  \
            const int nA1 = (PAR) ? aM1E : aM1O;                                  \
            const int nB0 = (PAR) ? bN0E : bN0O;                                  \
            const int nB1 = (PAR) ? bN1E : bN1O;                                  \
            afE[0] = *(const bf16x8*)&lds[nA0];                                   \
            afE[1] = *(const bf16x8*)&lds[nA0 + 8192];                            \
            afE[2] = *(const bf16x8*)&lds[nA1];                                   \
            afE[3] = *(const bf16x8*)&lds[nA1 + 8192];                            \
            b0[0] = *(const bf16x8*)&lds[nB0];                                    \
            b0[1] = *(const bf16x8*)&lds[nB0 + 8192];                             \
            b0[2] = *(const bf16x8*)&lds[nB1];                                    \
            b0[3] = *(const bf16x8*)&lds[nB1 + 8192];                             \
        }                                                                         \
        if (SP23) { GLL(ebc + sB0 + voffB, DBK0(PAR));                            \
                    GLL(ebc + sB0 + voffB + CDB, DBK0(PAR) + 1024); }             \
        sB0 += (((TT) & 7) == 5) ? 1047680 : 128;                                 \
        asm volatile("s_waitcnt " LGK3 ::: "memory");                             \
        __builtin_amdgcn_sched_barrier(0);                                        \
        __builtin_amdgcn_s_setprio(1);                                            \
        MFMA8(afO, b1, 1);                                                        \
        __builtin_amdgcn_s_setprio(0);                                            \
        __builtin_amdgcn_s_barrier();                                             \
        __builtin_amdgcn_sched_barrier(0);                                        \
    }

// ---------------- 256x256 pipelined 32x32x16-MFMA implicit-GEMM conv ----------------
__global__ __launch_bounds__(512, 2) void mfma_conv8_kernel(
    const __hip_bfloat16* __restrict__ xbf, const __hip_bfloat16* __restrict__ ebf,
    const float* __restrict__ bias, float* __restrict__ out) {
    __shared__ __align__(16) char lds[131072];

    const int tid = threadIdx.x;
    const int lane = tid & 63;
    const int wid = tid >> 6;      // 0..7
    const int wy = wid >> 2;       // 0..1 : M half (128 rows); also staging row-half
    const int wx = wid & 3;        // 0..3 : N quarter (64 cols)

    const int bid = blockIdx.x;
    const int wkid = ((bid & 7) << 7) + (bid >> 3);
    const int mtile = wkid >> 2;
    const int ntile = wkid & 3;
    const int n = mtile >> 4;
    const int sub = mtile & 15;
    const int qh0 = (sub >> 2) << 4;
    const int qw0 = (sub & 3) << 4;
    const int n0 = ntile << 8;

    const int slice = wid & 3;      // staging slice (8 channels)
    const int rowhalf = wid >> 2;   // staging row half (128 rows)

    f32x16 acc[8];
#pragma unroll
    for (int j = 0; j < 8; ++j) acc[j] = (f32x16)(0.f);

    // linear GLL dest base for this wave: slice*4096 + rowhalf*2048 within a half-slot
    char* ldsW = lds + (slice << 12) + (rowhalf << 11);
    const char* xbc = (const char*)xbf;
    const char* ebc = (const char*)ebf;

    // per-lane source row permutation: row = rowhalf*128 + c*64 + q,
    // q = lane ^ (lane&32 ? 4 : 0) ^ (slice&1 ? 4 : 0)
    const int q = lane ^ ((lane & 32) ? 4 : 0) ^ ((slice & 1) ? 4 : 0);
    // A: pixel (qh0 + rowhalf*8 + q>>4, qw0 + (q&15)); B: E row n0 + rowhalf*128 + q
    const int voffA =
        ((n * HP + qh0 + (rowhalf << 3) + (q >> 4)) * HP + qw0 + (q & 15)) * 1024 +
        (slice << 4);
    const int voffB = ((n0 + (rowhalf << 7) + q) << 10) + (slice << 4);

    // prologue-only generic stage (taps 0 only: tt2 <= 1)
    auto stage = [&](int s) {
        const int tt2 = s >> 2;
        const int part = s & 3;
        const int mat = part & 1;
        const int kh = part >> 1;
        const int slot = (((tt2 & 1) << 2) | (mat << 1) | kh) << 14;
        const int scal = tt2 * 128 + kh * 64;
#pragma unroll
        for (int c = 0; c < 2; ++c) {
            const char* src = mat == 0 ? (xbc + voffA + scal + c * CDA)
                                       : (ebc + voffB + scal + c * CDB);
            __builtin_amdgcn_global_load_lds(
                (const __attribute__((address_space(1))) unsigned int*)src,
                (__attribute__((address_space(3))) unsigned int*)(ldsW + slot + c * 1024),
                16, 0, 0);
        }
    };

    // read-side bases: lane l reads row (m0 + lane&31), slice 2ks + (lane>>5)
    const int sl = lane >> 5;
    const int l31 = lane & 31;
    const int sx = sl ? 64 : 0;
    const int aM0E = (sl << 12) + (wy << 11) + ((l31 << 4) ^ sx);
    const int aM1E = (sl << 12) + (wy << 11) + 512 + ((l31 << 4) ^ 64 ^ sx);
    const int aM0O = aM0E + 65536;
    const int aM1O = aM1E + 65536;
    const int bN0E = 32768 + (sl << 12) + (wx << 10) + ((l31 << 4) ^ sx);
    const int bN1E = 32768 + (sl << 12) + (wx << 10) + 512 + ((l31 << 4) ^ 64 ^ sx);
    const int bN0O = bN0E + 65536;
    const int bN1O = bN1E + 65536;

    // staging scalar byte offsets (chunk*128 + kh*64), validated deltas from R7
    int sA1 = 192, sA0 = 256, sB1 = 192, sB0 = 256;

    // ---- prologue: items 0..5; confirm items 0,1; read phase-0 frags ----
#pragma unroll
    for (int s = 0; s < 6; ++s) stage(s);
    asm volatile("s_waitcnt vmcnt(8)" ::: "memory");
    __builtin_amdgcn_s_barrier();
    __builtin_amdgcn_sched_barrier(0);

    bf16x8 afE[4], afO[4], b0[4], b1[4];
    afE[0] = *(const bf16x8*)&lds[aM0E];
    afE[1] = *(const bf16x8*)&lds[aM0E + 8192];
    afE[2] = *(const bf16x8*)&lds[aM1E];
    afE[3] = *(const bf16x8*)&lds[aM1E + 8192];
    b0[0] = *(const bf16x8*)&lds[bN0E];
    b0[1] = *(const bf16x8*)&lds[bN0E + 8192];
    b0[2] = *(const bf16x8*)&lds[bN1E];
    b0[3] = *(const bf16x8*)&lds[bN1E + 8192];

    // ---- main loop: tiles 0..67, then peeled tail 68..71 ----
#pragma unroll 1
    for (int tt = 0; tt < 68; tt += 2) {
        TILE_ITER(0, tt, 1, 1, "vmcnt(6)", "lgkmcnt(8)", 0);
        TILE_ITER(1, tt + 1, 1, 1, "vmcnt(6)", "lgkmcnt(8)", 0);
    }
    TILE_ITER(0, 68, 1, 1, "vmcnt(6)", "lgkmcnt(8)", 0);
    TILE_ITER(1, 69, 1, 1, "vmcnt(0)", "lgkmcnt(8)", 0);
    TILE_ITER(0, 70, 1, 0, "vmcnt(0)", "lgkmcnt(8)", 0);
    TILE_ITER(1, 71, 0, 0, "vmcnt(0)", "lgkmcnt(0)", 1);

    // ---- epilogue: bias + leaky-relu*sqrt2 + clamp, scatter to NCHW ----
    // C layout (m74/m101): col = lane&31, row = (reg&3) + 8*(reg>>2) + 4*(lane>>5)
    float bv[2];
#pragma unroll
    for (int nt = 0; nt < 2; ++nt)
        bv[nt] = bias[(n0 + (wx << 6) + (nt << 5) + l31) >> 2];
#pragma unroll
    for (int j = 0; j < 8; ++j) {
        const int mt = j >> 1, nt = j & 1;
        const int nn = n0 + (wx << 6) + (nt << 5) + l31;
        const int oc = nn >> 2, pu = (nn >> 1) & 1, pv = nn & 1;
#pragma unroll
        for (int v = 0; v < 16; ++v) {
            const int m = (wy << 7) + (mt << 5) + (v & 3) + ((v >> 2) << 3) + (sl << 2);
            const int qr = m >> 4, qc = m & 15;
            const int hb = 2 * (qh0 + qr), wb = 2 * (qw0 + qc);
            float val = acc[j][v] + bv[nt];
            val = (val >= 0.f ? val : 0.2f * val) * ACT_GAIN;
            val = fminf(fmaxf(val, -CLAMP_V), CLAMP_V);
            out[(((size_t)n * OUT_CH + oc) * HOUT + (hb + pu)) * HOUT + (wb + pv)] = val;
        }
    }
}

// ---------------- fallback (R1 proven path) if workspace too small ----------------
__global__ void build_e_kernel(const float* __restrict__ w, float* __restrict__ e_ws) {
    int gid = blockIdx.x * blockDim.x + threadIdx.x;
    if (gid >= OUT_CH * IN_CH) return;
    float wm[3][3];
    const float* wp = w + (size_t)gid * 9;
#pragma unroll
    for (int a = 0; a < 3; ++a)
#pragma unroll
        for (int b = 0; b < 3; ++b) wm[a][b] = wp[a * 3 + b] * WSCALE;
    float* op = e_ws + (size_t)gid * 36;
#pragma unroll
    for (int i = 0; i < 3; ++i)
#pragma unroll
        for (int j = 0; j < 3; ++j)
#pragma unroll
            for (int pu = 0; pu < 2; ++pu)
#pragma unroll
                for (int pv = 0; pv < 2; ++pv) {
                    float s = 0.f;
#pragma unroll
                    for (int a = 0; a < 3; ++a)
#pragma unroll
                        for (int b = 0; b < 3; ++b)
                            s += wm[a][b] * c_G[pu][i][a] * c_G[pv][j][b];
                    op[(i * 3 + j) * 4 + pu * 2 + pv] = s;
                }
}

#define OGB 8
#define CB 8
#define QT 16
__global__ __launch_bounds__(256) void fused_conv_kernel(
    const float* __restrict__ x, const float* __restrict__ e_ws,
    const float* __restrict__ bias, float* __restrict__ out) {
    __shared__ float sX[CB][18][19];
    __shared__ float4 sE[OGB * CB * 9];
    const int tid = threadIdx.x;
    const int o2 = tid >> 7;
    const int qy = (tid >> 3) & 15;
    const int qxp = tid & 7;
    const int tileIdx = blockIdx.x;
    const int hq0 = (tileIdx >> 2) * QT;
    const int wq0 = (tileIdx & 3) * QT;
    const int o0 = blockIdx.y * OGB;
    const int n = blockIdx.z;
    float4 acc[2][4];
#pragma unroll
    for (int q = 0; q < 2; ++q)
#pragma unroll
        for (int oo = 0; oo < 4; ++oo) acc[q][oo] = make_float4(0.f, 0.f, 0.f, 0.f);
    for (int c0 = 0; c0 < IN_CH; c0 += CB) {
        for (int idx = tid; idx < CB * 18 * 18; idx += 256) {
            int cc = idx / 324;
            int rem = idx - cc * 324;
            int r = rem / 18;
            int col = rem - r * 18;
            int h = hq0 - 1 + r;
            int ww = wq0 - 1 + col;
            float v = 0.f;
            if (h >= 0 && h < HIN && ww >= 0 && ww < HIN)
                v = x[(((size_t)n * IN_CH + (c0 + cc)) * HIN + h) * HIN + ww];
            sX[cc][r][col] = v;
        }
        {
            float* sEf = (float*)sE;
            for (int idx = tid; idx < OGB * CB * 36; idx += 256) {
                int ol = idx / (CB * 36);
                int rem = idx - ol * (CB * 36);
                sEf[ol * (CB * 36) + rem] =
                    e_ws[((size_t)(o0 + ol) * IN_CH + c0) * 36 + rem];
            }
        }
        __syncthreads();
#pragma unroll 1
        for (int cc = 0; cc < CB; ++cc) {
#pragma unroll
            for (int i = 0; i < 3; ++i) {
#pragma unroll
                for (int j = 0; j < 3; ++j) {
                    float xv0 = sX[cc][qy + i][2 * qxp + j];
                    float xv1 = sX[cc][qy + i][2 * qxp + 1 + j];
#pragma unroll
                    for (int oo = 0; oo < 4; ++oo) {
                        float4 e = sE[((o2 * 4 + oo) * CB + cc) * 9 + i * 3 + j];
                        acc[0][oo].x += xv0 * e.x; acc[0][oo].y += xv0 * e.y;
                        acc[0][oo].z += xv0 * e.z; acc[0][oo].w += xv0 * e.w;
                        acc[1][oo].x += xv1 * e.x; acc[1][oo].y += xv1 * e.y;
                        acc[1][oo].z += xv1 * e.z; acc[1][oo].w += xv1 * e.w;
                    }
                }
            }
        }
        __syncthreads();
    }
#pragma unroll
    for (int q = 0; q < 2; ++q) {
        int qx = 2 * qxp + q;
        int u0 = 2 * (hq0 + qy);
        int v0 = 2 * (wq0 + qx);
#pragma unroll
        for (int oo = 0; oo < 4; ++oo) {
            int o = o0 + o2 * 4 + oo;
            float b = bias[o];
            float vals[4] = {acc[q][oo].x, acc[q][oo].y, acc[q][oo].z, acc[q][oo].w};
#pragma unroll
            for (int p = 0; p < 4; ++p) {
                int pu = p >> 1, pv = p & 1;
                float v = vals[p] + b;
                v = (v >= 0.f ? v : 0.2f * v) * ACT_GAIN;
                v = fminf(fmaxf(v, -CLAMP_V), CLAMP_V);
                out[(((size_t)n * OUT_CH + o) * HOUT + (u0 + pu)) * HOUT + (v0 + pv)] = v;
            }
        }
    }
}

extern "C" void kernel_launch(void* const* d_in, const int* in_sizes, int n_in,
                              void* d_out, int out_size, void* d_ws, size_t ws_size,
                              hipStream_t stream) {
    const float* x = (const float*)d_in[0];
    const float* w = (const float*)d_in[1];
    const float* bias = (const float*)d_in[2];
    float* out = (float*)d_out;

    if (ws_size >= WS_NEED) {
        __hip_bfloat16* xbf = (__hip_bfloat16*)d_ws;
        __hip_bfloat16* ebf = (__hip_bfloat16*)((char*)d_ws + XBF_BYTES);
        xpose_kernel<<<dim3(8, HP, NIMG), 256, 0, stream>>>(x, xbf);
        build_ebf_kernel<<<(OUT_CH * IN_CH + 255) / 256, 256, 0, stream>>>(w, ebf);
        mfma_conv8_kernel<<<dim3(1024), 512, 0, stream>>>(xbf, ebf, bias, out);
    } else {
        float* e_ws = (float*)d_ws;
        build_e_kernel<<<(OUT_CH * IN_CH + 255) / 256, 256, 0, stream>>>(w, e_ws);
        dim3 grid(16, OUT_CH / OGB, NIMG);
        fused_conv_kernel<<<grid, 256, 0, stream>>>(x, e_ws, bias, out);
    }
}

// Round 10
// 629.586 us; speedup vs baseline: 1.1679x; 1.1679x over previous
//
#include <hip/hip_runtime.h>
#include <hip/hip_bf16.h>

#define NIMG 16
#define IN_CH 512
#define OUT_CH 256
#define HIN 64
#define HOUT 128
#define HP 66  // padded spatial (1-pixel zero halo)

#define WSCALE 0.014731391f      // 1/sqrt(9*512)
#define ACT_GAIN 1.41421356237f  // sqrt(2)
#define CLAMP_V 256.0f

typedef __attribute__((ext_vector_type(8))) short bf16x8;
typedef __attribute__((ext_vector_type(4))) float f32x4;
typedef __attribute__((ext_vector_type(16))) float f32x16;

// Parity tap matrices: G[p][i][a] = u[a-1+2i-p], u = {1,3,3,1}/4 (0 if OOR)
__device__ __constant__ float c_G[2][3][3] = {
    {{0.00f, 0.25f, 0.75f}, {0.75f, 0.75f, 0.25f}, {0.25f, 0.00f, 0.00f}},
    {{0.00f, 0.00f, 0.25f}, {0.25f, 0.75f, 0.75f}, {0.75f, 0.25f, 0.00f}}
};

// xbf2: [(n*64+sg)][hp 66][wp 66] x 16B (8 ch per slice sg)
#define XBF_BYTES ((size_t)NIMG * 64 * HP * HP * 16)       // 71,368,704
// ebf2: [tap 9][sg 64][row 1024] x 16B
#define EBF_BYTES ((size_t)9 * 64 * 1024 * 16)             //  9,437,184
#define WS_NEED (XBF_BYTES + EBF_BYTES)

// ---------------- x -> slice-major padded bf16 tiles ----------------
__global__ __launch_bounds__(256) void xpose_kernel(const float* __restrict__ x,
                                                    __hip_bfloat16* __restrict__ xbf) {
    const int n = blockIdx.z;
    const int hp = blockIdx.y;        // 0..65
    const int c0 = blockIdx.x << 6;   // 8 slices of 8 channels
    const int tid = threadIdx.x;
    const int sgb = c0 >> 3;
    const bf16x8 zero = {0, 0, 0, 0, 0, 0, 0, 0};

    if (hp == 0 || hp == HP - 1) {
        for (int idx = tid; idx < 8 * HP; idx += 256) {
            int s3 = idx / HP, wp = idx - s3 * HP;
            size_t a = (((size_t)(n * 64 + sgb + s3) * HP + hp) * HP + wp);
            *(bf16x8*)((char*)xbf + a * 16) = zero;
        }
        return;
    }
    __shared__ float tile[64][65];
    {
        int cc = tid >> 6, w = tid & 63;
        for (int cb = 0; cb < 64; cb += 4)
            tile[cb + cc][w] =
                x[(((size_t)n * IN_CH + c0 + cb + cc) * HIN + (hp - 1)) * HIN + w];
    }
    __syncthreads();
    {
        int s3 = tid >> 5, wq = tid & 31;
#pragma unroll
        for (int wb = 0; wb < 64; wb += 32) {
            int wimg = wb + wq;
            bf16x8 v;
#pragma unroll
            for (int k = 0; k < 8; ++k) {
                __hip_bfloat16 b = __float2bfloat16(tile[s3 * 8 + k][wimg]);
                v[k] = *reinterpret_cast<short*>(&b);
            }
            size_t a = (((size_t)(n * 64 + sgb + s3) * HP + hp) * HP + (wimg + 1));
            *(bf16x8*)((char*)xbf + a * 16) = v;
        }
        if (tid < 16) {
            int s3h = tid >> 1, wph = (tid & 1) ? (HP - 1) : 0;
            size_t a = (((size_t)(n * 64 + sgb + s3h) * HP + hp) * HP + wph);
            *(bf16x8*)((char*)xbf + a * 16) = zero;
        }
    }
}

// ---------------- w -> E bf16 slice-major: [tap][sg][row(oc*4+par)] x 16B ----------------
__global__ __launch_bounds__(256) void build_ebf_kernel(const float* __restrict__ w,
                                                        __hip_bfloat16* __restrict__ ebf) {
    int gid = blockIdx.x * 256 + threadIdx.x;  // oc*512 + c
    if (gid >= OUT_CH * IN_CH) return;
    int oc = gid >> 9, c = gid & 511;
    int sg = c >> 3, ce = c & 7;
    float wm[3][3];
    const float* wp = w + (size_t)gid * 9;
#pragma unroll
    for (int a = 0; a < 3; ++a)
#pragma unroll
        for (int b = 0; b < 3; ++b) wm[a][b] = wp[a * 3 + b] * WSCALE;
#pragma unroll
    for (int i = 0; i < 3; ++i)
#pragma unroll
        for (int j = 0; j < 3; ++j)
#pragma unroll
            for (int pu = 0; pu < 2; ++pu)
#pragma unroll
                for (int pv = 0; pv < 2; ++pv) {
                    float s = 0.f;
#pragma unroll
                    for (int a = 0; a < 3; ++a)
#pragma unroll
                        for (int b = 0; b < 3; ++b)
                            s += wm[a][b] * c_G[pu][i][a] * c_G[pv][j][b];
                    int row = oc * 4 + pu * 2 + pv;
                    ebf[(((size_t)(i * 3 + j) * 64 + sg) * 1024 + row) * 8 + ce] =
                        __float2bfloat16(s);
                }
}

// 8 MFMAs of 32x32x16: AF[mt2*2+ks], BF[nt*2+ks]; acc[MH*4 + mt2*2 + nt].
#define MFMA8(AF, BF, MH)                                                                   \
    do {                                                                                    \
        acc[(MH)*4+0] = __builtin_amdgcn_mfma_f32_32x32x16_bf16((AF)[0], (BF)[0], acc[(MH)*4+0], 0, 0, 0); \
        acc[(MH)*4+1] = __builtin_amdgcn_mfma_f32_32x32x16_bf16((AF)[0], (BF)[2], acc[(MH)*4+1], 0, 0, 0); \
        acc[(MH)*4+2] = __builtin_amdgcn_mfma_f32_32x32x16_bf16((AF)[2], (BF)[0], acc[(MH)*4+2], 0, 0, 0); \
        acc[(MH)*4+3] = __builtin_amdgcn_mfma_f32_32x32x16_bf16((AF)[2], (BF)[2], acc[(MH)*4+3], 0, 0, 0); \
        acc[(MH)*4+0] = __builtin_amdgcn_mfma_f32_32x32x16_bf16((AF)[1], (BF)[1], acc[(MH)*4+0], 0, 0, 0); \
        acc[(MH)*4+1] = __builtin_amdgcn_mfma_f32_32x32x16_bf16((AF)[1], (BF)[3], acc[(MH)*4+1], 0, 0, 0); \
        acc[(MH)*4+2] = __builtin_amdgcn_mfma_f32_32x32x16_bf16((AF)[3], (BF)[1], acc[(MH)*4+2], 0, 0, 0); \
        acc[(MH)*4+3] = __builtin_amdgcn_mfma_f32_32x32x16_bf16((AF)[3], (BF)[3], acc[(MH)*4+3], 0, 0, 0); \
    } while (0)

// GLL-pair src deltas (bytes): +4 quad-rows (A) / +64 rows (B) in new layouts
#define CDA 4224     // 4 rows * 66 * 16B
#define CDB 1024     // 64 rows * 16B
// staging scalar advance constants (bytes)
#define ASTEP 557568      // +8 slices * 69696
#define AJ_FJ (-3902960)  // -56 slices + fj(+16)
#define AJ_FI (-3901952)  // -56 slices + fi(+1056) + fj(-32)
#define BSTEP 131072      // +8 slices * 16384 (uniform incl. tap boundary)
// LDS dst slot constants (bytes), PAR literal
#define DAK1(PAR) (((((PAR) ^ 1) << 2) | 1) << 14)
#define DBK1(PAR) (((((PAR) ^ 1) << 2) | 3) << 14)
#define DAK0(PAR) ((((PAR) << 2) | 0) << 14)
#define DBK0(PAR) ((((PAR) << 2) | 2) << 14)

#define GLL(SRC, DSTOFF)                                                          \
    __builtin_amdgcn_global_load_lds(                                             \
        (const __attribute__((address_space(1))) unsigned int*)(SRC),             \
        (__attribute__((address_space(3))) unsigned int*)(ldsW + (DSTOFF)), 16, 0, 0)

// One K-tile (BK=64), 4 phases, PAR = tile parity LITERAL.
// Schedule/ledger identical to R6-R9 (lgkm 4/8/4/8, vmcnt at p0/p2, 1 barrier/phase).
// LDS layout & read addressing identical to R9 (proven conflict-free, refchecked).
// Staging sources are now CONTIGUOUS runs (A: 4x256B, B: 1x1KB) because xbf2/ebf2
// are stored slice-major in exactly the LDS staging order.
#define TILE_ITER(PAR, TT, SP01, SP23, VMS, LGK3, LAST)                           \
    {                                                                             \
        const int A0 = (PAR) ? aM0O : aM0E;                                       \
        const int A1 = (PAR) ? aM1O : aM1E;                                       \
        const int B0 = (PAR) ? bN0O : bN0E;                                       \
        const int B1 = (PAR) ? bN1O : bN1E;                                       \
        /* ---- p0: compute (kh0,mh0) afE,b0; prefetch afO<-(kh0,mh1); stage AK1 */\
        afO[0] = *(const bf16x8*)&lds[A0 + 1024];                                 \
        afO[1] = *(const bf16x8*)&lds[A0 + 1024 + 8192];                          \
        afO[2] = *(const bf16x8*)&lds[A1 + 1024];                                 \
        afO[3] = *(const bf16x8*)&lds[A1 + 1024 + 8192];                          \
        if (SP01) { GLL(xbc + sA1 + voffA, DAK1(PAR));                            \
                    GLL(xbc + sA1 + voffA + CDA, DAK1(PAR) + 1024); }             \
        sA1 += (((TT) & 7) == 6) ? (((TT) == 22 || (TT) == 46) ? AJ_FI : AJ_FJ)   \
                                 : ASTEP;                                         \
        asm volatile("s_waitcnt lgkmcnt(4)" ::: "memory");                        \
        __builtin_amdgcn_sched_barrier(0);                                        \
        __builtin_amdgcn_s_setprio(1);                                            \
        MFMA8(afE, b0, 0);                                                        \
        __builtin_amdgcn_s_setprio(0);                                            \
        asm volatile("s_waitcnt " VMS ::: "memory");                              \
        __builtin_amdgcn_s_barrier();                                             \
        __builtin_amdgcn_sched_barrier(0);                                        \
        /* ---- p1: compute (kh0,mh1) afO,b0; prefetch afE<-(kh1,mh0)+b1; BK1 */  \
        afE[0] = *(const bf16x8*)&lds[A0 + 16384];                                \
        afE[1] = *(const bf16x8*)&lds[A0 + 16384 + 8192];                         \
        afE[2] = *(const bf16x8*)&lds[A1 + 16384];                                \
        afE[3] = *(const bf16x8*)&lds[A1 + 16384 + 8192];                         \
        b1[0] = *(const bf16x8*)&lds[B0 + 16384];                                 \
        b1[1] = *(const bf16x8*)&lds[B0 + 16384 + 8192];                          \
        b1[2] = *(const bf16x8*)&lds[B1 + 16384];                                 \
        b1[3] = *(const bf16x8*)&lds[B1 + 16384 + 8192];                          \
        if (SP01) { GLL(ebc + sB1 + voffB, DBK1(PAR));                            \
                    GLL(ebc + sB1 + voffB + CDB, DBK1(PAR) + 1024); }             \
        sB1 += BSTEP;                                                             \
        asm volatile("s_waitcnt lgkmcnt(8)" ::: "memory");                        \
        __builtin_amdgcn_sched_barrier(0);                                        \
        __builtin_amdgcn_s_setprio(1);                                            \
        MFMA8(afO, b0, 1);                                                        \
        __builtin_amdgcn_s_setprio(0);                                            \
        __builtin_amdgcn_s_barrier();                                             \
        __builtin_amdgcn_sched_barrier(0);                                        \
        /* ---- p2: compute (kh1,mh0) afE,b1; prefetch afO<-(kh1,mh1); stage AK0 */\
        afO[0] = *(const bf16x8*)&lds[A0 + 16384 + 1024];                         \
        afO[1] = *(const bf16x8*)&lds[A0 + 16384 + 1024 + 8192];                  \
        afO[2] = *(const bf16x8*)&lds[A1 + 16384 + 1024];                         \
        afO[3] = *(const bf16x8*)&lds[A1 + 16384 + 1024 + 8192];                  \
        if (SP23) { GLL(xbc + sA0 + voffA, DAK0(PAR));                            \
                    GLL(xbc + sA0 + voffA + CDA, DAK0(PAR) + 1024); }             \
        sA0 += (((TT) & 7) == 5) ? (((TT) == 21 || (TT) == 45) ? AJ_FI : AJ_FJ)   \
                                 : ASTEP;                                         \
        asm volatile("s_waitcnt lgkmcnt(4)" ::: "memory");                        \
        __builtin_amdgcn_sched_barrier(0);                                        \
        __builtin_amdgcn_s_setprio(1);                                            \
        MFMA8(afE, b1, 0);                                                        \
        __builtin_amdgcn_s_setprio(0);                                            \
        asm volatile("s_waitcnt " VMS ::: "memory");                              \
        __builtin_amdgcn_s_barrier();                                             \
        __builtin_amdgcn_sched_barrier(0);                                        \
        /* ---- p3: compute (kh1,mh1) afO,b1; prefetch next tile afE,b0; BK0 */   \
        if (!(LAST)) {                                                            \
            const int nA0 = (PAR) ? aM0E : aM0O;                                  \
            const int nA1 = (PAR) ? aM1E : aM1O;                                  \
            const int nB0 = (PAR) ? bN0E : bN0O;                                  \
            const int nB1 = (PAR) ? bN1E : bN1O;                                  \
            afE[0] = *(const bf16x8*)&lds[nA0];                                   \
            afE[1] = *(const bf16x8*)&lds[nA0 + 8192];                            \
            afE[2] = *(const bf16x8*)&lds[nA1];                                   \
            afE[3] = *(const bf16x8*)&lds[nA1 + 8192];                            \
            b0[0] = *(const bf16x8*)&lds[nB0];                                    \
            b0[1] = *(const bf16x8*)&lds[nB0 + 8192];                             \
            b0[2] = *(const bf16x8*)&lds[nB1];                                    \
            b0[3] = *(const bf16x8*)&lds[nB1 + 8192];                             \
        }                                                                         \
        if (SP23) { GLL(ebc + sB0 + voffB, DBK0(PAR));                            \
                    GLL(ebc + sB0 + voffB + CDB, DBK0(PAR) + 1024); }             \
        sB0 += BSTEP;                                                             \
        asm volatile("s_waitcnt " LGK3 ::: "memory");                             \
        __builtin_amdgcn_sched_barrier(0);                                        \
        __builtin_amdgcn_s_setprio(1);                                            \
        MFMA8(afO, b1, 1);                                                        \
        __builtin_amdgcn_s_setprio(0);                                            \
        __builtin_amdgcn_s_barrier();                                             \
        __builtin_amdgcn_sched_barrier(0);                                        \
    }

// ---------------- 256x256 pipelined 32x32x16-MFMA implicit-GEMM conv ----------------
__global__ __launch_bounds__(512, 2) void mfma_conv8_kernel(
    const __hip_bfloat16* __restrict__ xbf, const __hip_bfloat16* __restrict__ ebf,
    const float* __restrict__ bias, float* __restrict__ out) {
    __shared__ __align__(16) char lds[131072];

    const int tid = threadIdx.x;
    const int lane = tid & 63;
    const int wid = tid >> 6;      // 0..7
    const int wy = wid >> 2;       // 0..1 : M half (128 rows); also staging row-half
    const int wx = wid & 3;        // 0..3 : N quarter (64 cols)

    const int bid = blockIdx.x;
    const int wkid = ((bid & 7) << 7) + (bid >> 3);
    const int mtile = wkid >> 2;
    const int ntile = wkid & 3;
    const int n = mtile >> 4;
    const int sub = mtile & 15;
    const int qh0 = (sub >> 2) << 4;
    const int qw0 = (sub & 3) << 4;
    const int n0 = ntile << 8;

    const int slice = wid & 3;      // staging slice (8 channels)
    const int rowhalf = wid >> 2;   // staging row half

    f32x16 acc[8];
#pragma unroll
    for (int j = 0; j < 8; ++j) acc[j] = (f32x16)(0.f);

    // linear GLL dest base for this wave: slice*4096 + rowhalf*2048 within a half-slot
    char* ldsW = lds + (slice << 12) + (rowhalf << 11);
    const char* xbc = (const char*)xbf;
    const char* ebc = (const char*)ebf;

    // per-lane source row permutation (identical to R9 -> identical LDS content)
    const int q = lane ^ ((lane & 32) ? 4 : 0) ^ ((slice & 1) ? 4 : 0);
    // A: xbf2 addr = ((n*64+slice+sgoff)*HP + qh0+fi+qr)*HP + qw0+fj+qc, x16B
    const int voffA =
        ((((n << 6) + slice) * HP + qh0 + (rowhalf << 3) + (q >> 4)) * HP + qw0 +
         (q & 15)) * 16;
    // B: ebf2 addr = ((tap*64 + slice+sgoff)*1024 + n0 + row)*16
    const int voffB = (slice << 14) + ((n0 + (rowhalf << 7) + q) << 4);

    // prologue-only generic stage (tiles 0,1; tap 0)
    auto stage = [&](int s) {
        const int tt2 = s >> 2;
        const int part = s & 3;
        const int mat = part & 1;
        const int kh = part >> 1;
        const int slot = (((tt2 & 1) << 2) | (mat << 1) | kh) << 14;
        const int sgoff = (tt2 << 3) + (kh << 2);  // slices
#pragma unroll
        for (int c = 0; c < 2; ++c) {
            const char* src = mat == 0 ? (xbc + voffA + sgoff * 69696 + c * CDA)
                                       : (ebc + voffB + sgoff * 16384 + c * CDB);
            __builtin_amdgcn_global_load_lds(
                (const __attribute__((address_space(1))) unsigned int*)src,
                (__attribute__((address_space(3))) unsigned int*)(ldsW + slot + c * 1024),
                16, 0, 0);
        }
    };

    // read-side bases (verbatim R9 - proven conflict-free & correct)
    const int sl = lane >> 5;
    const int l31 = lane & 31;
    const int sx = sl ? 64 : 0;
    const int aM0E = (sl << 12) + (wy << 11) + ((l31 << 4) ^ sx);
    const int aM1E = (sl << 12) + (wy << 11) + 512 + ((l31 << 4) ^ 64 ^ sx);
    const int aM0O = aM0E + 65536;
    const int aM1O = aM1E + 65536;
    const int bN0E = 32768 + (sl << 12) + (wx << 10) + ((l31 << 4) ^ sx);
    const int bN1E = 32768 + (sl << 12) + (wx << 10) + 512 + ((l31 << 4) ^ 64 ^ sx);
    const int bN0O = bN0E + 65536;
    const int bN1O = bN1E + 65536;

    // staging scalar byte offsets: (chunk*8 + kh*4) slices [+ tap offset for A pixels]
    int sA1 = 12 * 69696;   // tile 1, kh1
    int sA0 = 16 * 69696;   // tile 2, kh0
    int sB1 = 12 * 16384;   // tile 1, kh1
    int sB0 = 16 * 16384;   // tile 2, kh0

    // ---- prologue: items 0..5; confirm items 0,1; read phase-0 frags ----
#pragma unroll
    for (int s = 0; s < 6; ++s) stage(s);
    asm volatile("s_waitcnt vmcnt(8)" ::: "memory");
    __builtin_amdgcn_s_barrier();
    __builtin_amdgcn_sched_barrier(0);

    bf16x8 afE[4], afO[4], b0[4], b1[4];
    afE[0] = *(const bf16x8*)&lds[aM0E];
    afE[1] = *(const bf16x8*)&lds[aM0E + 8192];
    afE[2] = *(const bf16x8*)&lds[aM1E];
    afE[3] = *(const bf16x8*)&lds[aM1E + 8192];
    b0[0] = *(const bf16x8*)&lds[bN0E];
    b0[1] = *(const bf16x8*)&lds[bN0E + 8192];
    b0[2] = *(const bf16x8*)&lds[bN1E];
    b0[3] = *(const bf16x8*)&lds[bN1E + 8192];

    // ---- main loop: tiles 0..67, then peeled tail 68..71 ----
#pragma unroll 1
    for (int tt = 0; tt < 68; tt += 2) {
        TILE_ITER(0, tt, 1, 1, "vmcnt(6)", "lgkmcnt(8)", 0);
        TILE_ITER(1, tt + 1, 1, 1, "vmcnt(6)", "lgkmcnt(8)", 0);
    }
    TILE_ITER(0, 68, 1, 1, "vmcnt(6)", "lgkmcnt(8)", 0);
    TILE_ITER(1, 69, 1, 1, "vmcnt(0)", "lgkmcnt(8)", 0);
    TILE_ITER(0, 70, 1, 0, "vmcnt(0)", "lgkmcnt(8)", 0);
    TILE_ITER(1, 71, 0, 0, "vmcnt(0)", "lgkmcnt(0)", 1);

    // ---- epilogue: bias + leaky-relu*sqrt2 + clamp, scatter to NCHW ----
    // C layout (m74/m101): col = lane&31, row = (reg&3) + 8*(reg>>2) + 4*(lane>>5)
    float bv[2];
#pragma unroll
    for (int nt = 0; nt < 2; ++nt)
        bv[nt] = bias[(n0 + (wx << 6) + (nt << 5) + l31) >> 2];
#pragma unroll
    for (int j = 0; j < 8; ++j) {
        const int mt = j >> 1, nt = j & 1;
        const int nn = n0 + (wx << 6) + (nt << 5) + l31;
        const int oc = nn >> 2, pu = (nn >> 1) & 1, pv = nn & 1;
#pragma unroll
        for (int v = 0; v < 16; ++v) {
            const int m = (wy << 7) + (mt << 5) + (v & 3) + ((v >> 2) << 3) + (sl << 2);
            const int qr = m >> 4, qc = m & 15;
            const int hb = 2 * (qh0 + qr), wb = 2 * (qw0 + qc);
            float val = acc[j][v] + bv[nt];
            val = (val >= 0.f ? val : 0.2f * val) * ACT_GAIN;
            val = fminf(fmaxf(val, -CLAMP_V), CLAMP_V);
            out[(((size_t)n * OUT_CH + oc) * HOUT + (hb + pu)) * HOUT + (wb + pv)] = val;
        }
    }
}

// ---------------- fallback (R1 proven path) if workspace too small ----------------
__global__ void build_e_kernel(const float* __restrict__ w, float* __restrict__ e_ws) {
    int gid = blockIdx.x * blockDim.x + threadIdx.x;
    if (gid >= OUT_CH * IN_CH) return;
    float wm[3][3];
    const float* wp = w + (size_t)gid * 9;
#pragma unroll
    for (int a = 0; a < 3; ++a)
#pragma unroll
        for (int b = 0; b < 3; ++b) wm[a][b] = wp[a * 3 + b] * WSCALE;
    float* op = e_ws + (size_t)gid * 36;
#pragma unroll
    for (int i = 0; i < 3; ++i)
#pragma unroll
        for (int j = 0; j < 3; ++j)
#pragma unroll
            for (int pu = 0; pu < 2; ++pu)
#pragma unroll
                for (int pv = 0; pv < 2; ++pv) {
                    float s = 0.f;
#pragma unroll
                    for (int a = 0; a < 3; ++a)
#pragma unroll
                        for (int b = 0; b < 3; ++b)
                            s += wm[a][b] * c_G[pu][i][a] * c_G[pv][j][b];
                    op[(i * 3 + j) * 4 + pu * 2 + pv] = s;
                }
}

#define OGB 8
#define CB 8
#define QT 16
__global__ __launch_bounds__(256) void fused_conv_kernel(
    const float* __restrict__ x, const float* __restrict__ e_ws,
    const float* __restrict__ bias, float* __restrict__ out) {
    __shared__ float sX[CB][18][19];
    __shared__ float4 sE[OGB * CB * 9];
    const int tid = threadIdx.x;
    const int o2 = tid >> 7;
    const int qy = (tid >> 3) & 15;
    const int qxp = tid & 7;
    const int tileIdx = blockIdx.x;
    const int hq0 = (tileIdx >> 2) * QT;
    const int wq0 = (tileIdx & 3) * QT;
    const int o0 = blockIdx.y * OGB;
    const int n = blockIdx.z;
    float4 acc[2][4];
#pragma unroll
    for (int q = 0; q < 2; ++q)
#pragma unroll
        for (int oo = 0; oo < 4; ++oo) acc[q][oo] = make_float4(0.f, 0.f, 0.f, 0.f);
    for (int c0 = 0; c0 < IN_CH; c0 += CB) {
        for (int idx = tid; idx < CB * 18 * 18; idx += 256) {
            int cc = idx / 324;
            int rem = idx - cc * 324;
            int r = rem / 18;
            int col = rem - r * 18;
            int h = hq0 - 1 + r;
            int ww = wq0 - 1 + col;
            float v = 0.f;
            if (h >= 0 && h < HIN && ww >= 0 && ww < HIN)
                v = x[(((size_t)n * IN_CH + (c0 + cc)) * HIN + h) * HIN + ww];
            sX[cc][r][col] = v;
        }
        {
            float* sEf = (float*)sE;
            for (int idx = tid; idx < OGB * CB * 36; idx += 256) {
                int ol = idx / (CB * 36);
                int rem = idx - ol * (CB * 36);
                sEf[ol * (CB * 36) + rem] =
                    e_ws[((size_t)(o0 + ol) * IN_CH + c0) * 36 + rem];
            }
        }
        __syncthreads();
#pragma unroll 1
        for (int cc = 0; cc < CB; ++cc) {
#pragma unroll
            for (int i = 0; i < 3; ++i) {
#pragma unroll
                for (int j = 0; j < 3; ++j) {
                    float xv0 = sX[cc][qy + i][2 * qxp + j];
                    float xv1 = sX[cc][qy + i][2 * qxp + 1 + j];
#pragma unroll
                    for (int oo = 0; oo < 4; ++oo) {
                        float4 e = sE[((o2 * 4 + oo) * CB + cc) * 9 + i * 3 + j];
                        acc[0][oo].x += xv0 * e.x; acc[0][oo].y += xv0 * e.y;
                        acc[0][oo].z += xv0 * e.z; acc[0][oo].w += xv0 * e.w;
                        acc[1][oo].x += xv1 * e.x; acc[1][oo].y += xv1 * e.y;
                        acc[1][oo].z += xv1 * e.z; acc[1][oo].w += xv1 * e.w;
                    }
                }
            }
        }
        __syncthreads();
    }
#pragma unroll
    for (int q = 0; q < 2; ++q) {
        int qx = 2 * qxp + q;
        int u0 = 2 * (hq0 + qy);
        int v0 = 2 * (wq0 + qx);
#pragma unroll
        for (int oo = 0; oo < 4; ++oo) {
            int o = o0 + o2 * 4 + oo;
            float b = bias[o];
            float vals[4] = {acc[q][oo].x, acc[q][oo].y, acc[q][oo].z, acc[q][oo].w};
#pragma unroll
            for (int p = 0; p < 4; ++p) {
                int pu = p >> 1, pv = p & 1;
                float v = vals[p] + b;
                v = (v >= 0.f ? v : 0.2f * v) * ACT_GAIN;
                v = fminf(fmaxf(v, -CLAMP_V), CLAMP_V);
                out[(((size_t)n * OUT_CH + o) * HOUT + (u0 + pu)) * HOUT + (v0 + pv)] = v;
            }
        }
    }
}

extern "C" void kernel_launch(void* const* d_in, const int* in_sizes, int n_in,
                              void* d_out, int out_size, void* d_ws, size_t ws_size,
                              hipStream_t stream) {
    const float* x = (const float*)d_in[0];
    const float* w = (const float*)d_in[1];
    const float* bias = (const float*)d_in[2];
    float* out = (float*)d_out;

    if (ws_size >= WS_NEED) {
        __hip_bfloat16* xbf = (__hip_bfloat16*)d_ws;
        __hip_bfloat16* ebf = (__hip_bfloat16*)((char*)d_ws + XBF_BYTES);
        xpose_kernel<<<dim3(8, HP, NIMG), 256, 0, stream>>>(x, xbf);
        build_ebf_kernel<<<(OUT_CH * IN_CH + 255) / 256, 256, 0, stream>>>(w, ebf);
        mfma_conv8_kernel<<<dim3(1024), 512, 0, stream>>>(xbf, ebf, bias, out);
    } else {
        float* e_ws = (float*)d_ws;
        build_e_kernel<<<(OUT_CH * IN_CH + 255) / 256, 256, 0, stream>>>(w, e_ws);
        dim3 grid(16, OUT_CH / OGB, NIMG);
        fused_conv_kernel<<<grid, 256, 0, stream>>>(x, e_ws, bias, out);
    }
}